// Round 12
// baseline (276.732 us; speedup 1.0000x reference)
//
#include <hip/hip_runtime.h>
#include <stdint.h>

#define HEADS 3
#define HID 128
#define FDIM (HEADS * HID)   // 384

typedef __attribute__((ext_vector_type(8))) short bf16x8;
typedef __attribute__((ext_vector_type(4))) float f32x4;

__device__ __forceinline__ float lrelu(float x) { return x >= 0.f ? x : 0.2f * x; }
__device__ __forceinline__ float rrelu(float x) {
    const float SLOPE = (1.0f / 8.0f + 1.0f / 3.0f) * 0.5f;
    return x >= 0.f ? x : SLOPE * x;
}
__device__ __forceinline__ unsigned short f2bf(float f) {
    union { float f; unsigned u; } c; c.f = f;
    unsigned r = c.u + 0x7FFF + ((c.u >> 16) & 1);   // RNE
    return (unsigned short)(r >> 16);
}
__device__ __forceinline__ float bflo(unsigned u) {
    union { unsigned u; float f; } c; c.u = u << 16; return c.f;
}
__device__ __forceinline__ float bfhi(unsigned u) {
    union { unsigned u; float f; } c; c.u = u & 0xffff0000u; return c.f;
}

__device__ __forceinline__ void gload_lds16(const void* g, void* l) {
    __builtin_amdgcn_global_load_lds(
        (const __attribute__((address_space(1))) void*)g,
        (__attribute__((address_space(3))) void*)l, 16, 0, 0);
}

// ---------------- CSR build (counting sort by dst) ----------------

__global__ void k_hist(const int* __restrict__ dst, int E, int* __restrict__ cnt) {
    for (int i = blockIdx.x * blockDim.x + threadIdx.x; i < E; i += gridDim.x * blockDim.x)
        atomicAdd(&cnt[dst[i]], 1);
}

#define SC_T 256
#define SC_E 8
#define SC_CHUNK (SC_T * SC_E)   // 2048

__global__ __launch_bounds__(SC_T) void k_scan1(const int* __restrict__ cnt,
                                                int* __restrict__ exc,
                                                int* __restrict__ bsum, int n) {
    __shared__ int sm[SC_T];
    int b = blockIdx.x, t = threadIdx.x;
    int base = b * SC_CHUNK + t * SC_E;
    int v[SC_E];
    int s = 0;
#pragma unroll
    for (int i = 0; i < SC_E; i++) {
        int idx = base + i;
        v[i] = (idx < n) ? cnt[idx] : 0;
        s += v[i];
    }
    sm[t] = s;
    __syncthreads();
    for (int off = 1; off < SC_T; off <<= 1) {
        int x = (t >= off) ? sm[t - off] : 0;
        __syncthreads();
        sm[t] += x;
        __syncthreads();
    }
    int run = sm[t] - s;
    if (t == SC_T - 1) bsum[b] = sm[t];
#pragma unroll
    for (int i = 0; i < SC_E; i++) {
        int idx = base + i;
        if (idx < n) exc[idx] = run;
        run += v[i];
    }
}

__global__ __launch_bounds__(256) void k_scan2(const int* __restrict__ bsum,
                                               int* __restrict__ bpre, int nb) {
    __shared__ int sm[256];
    int t = threadIdx.x;
    int v = (t < nb) ? bsum[t] : 0;
    sm[t] = v;
    __syncthreads();
    for (int off = 1; off < 256; off <<= 1) {
        int x = (t >= off) ? sm[t - off] : 0;
        __syncthreads();
        sm[t] += x;
        __syncthreads();
    }
    if (t < nb) bpre[t + 1] = sm[t];
    if (t == 0) bpre[0] = 0;
}

__global__ void k_scan3(int* __restrict__ offs, const int* __restrict__ bpre,
                        int* __restrict__ cursor, int n, int nb) {
    int i = blockIdx.x * blockDim.x + threadIdx.x;
    if (i < n) {
        int o = offs[i] + bpre[i / SC_CHUNK];
        offs[i] = o;
        cursor[i] = o;
    }
    if (i == 0) offs[n] = bpre[nb];
}

__global__ void k_scatter(const int* __restrict__ src, const int* __restrict__ dst, int E,
                          int* __restrict__ cursor, int* __restrict__ ssrc,
                          int* __restrict__ sdst) {
    for (int i = blockIdx.x * blockDim.x + threadIdx.x; i < E; i += gridDim.x * blockDim.x) {
        int d = dst[i];
        int p = atomicAdd(&cursor[d], 1);
        ssrc[p] = src[i];
        sdst[p] = d;
    }
}

// ---------------- bf16 convert: W1^T and W2^T in one dispatch ----------------

__global__ void k_cvt_wt2(const float* __restrict__ W1, unsigned short* __restrict__ W1T,
                          const float* __restrict__ W2, unsigned short* __restrict__ W2T) {
    int b = blockIdx.x;
    if (b < FDIM) {
        for (int k = threadIdx.x; k < 256; k += blockDim.x)
            W1T[(size_t)b * 256 + k] = f2bf(W1[(size_t)k * FDIM + b]);
    } else {
        int n = b - FDIM;
        for (int k = threadIdx.x; k < 128; k += blockDim.x)
            W2T[(size_t)n * 128 + k] = f2bf(W2[(size_t)k * FDIM + n]);
    }
}

// ---------------- A-resident bf16 MFMA GEMM (64 rows x 384 cols per block) ----------
// Full A tile (64 x K bf16, padded stride K+8) staged in LDS once; 3 heads looped
// in-block with double-buffered B staging (stage-ahead, vmcnt(0) one iter behind).
// es/ed are [N,4] stride-4.

template <bool F32A>
__global__ __launch_bounds__(256) void k_gemm(
    const void* __restrict__ Ap0, const void* __restrict__ Ap1, int Nn,
    const unsigned short* __restrict__ BT,
    unsigned short* __restrict__ C,
    int K, int Ncols,
    const float* __restrict__ asrc, const float* __restrict__ adst,
    float* __restrict__ es, float* __restrict__ ed, int Nnodes) {
    __shared__ __align__(16) unsigned short As[64 * 264];     // K<=256, stride K+8
    __shared__ __align__(16) unsigned short Bs[2][128 * 32];
    __shared__ float esP[64][2], edP[64][2];
    int tid = threadIdx.x;
    int w = tid >> 6, lane = tid & 63;
    int row0 = blockIdx.x * 64;
    int wr = w >> 1, wc = w & 1;     // wave: rows wr*32..+32, cols wc*64..+64
    int KP = K + 8;
    int KS = K >> 5;                 // K-steps of 32

    int frow = lane & 15;
    int fk = (lane >> 4) * 8;

    // ---- stage full A tile into LDS (bf16, padded) ----
    if (F32A) {
        const float* zf = (const float*)Ap0;
        const float* xf = (const float*)Ap1;
#pragma unroll 8
        for (int i = 0; i < 16; i++) {           // 4096 float4 slots
            int idx = i * 256 + tid;
            int row = idx >> 6;                  // 64 slots per row (256 cols)
            int c4 = (idx & 63) * 4;
            int gr = row0 + row;
            float4 v = make_float4(0.f, 0.f, 0.f, 0.f);
            if (gr < Nn) {
                const float* sp = (c4 < 128) ? zf + (size_t)gr * 128 + c4
                                             : xf + (size_t)gr * 128 + (c4 - 128);
                v = *(const float4*)sp;
            }
            unsigned short o[4] = {f2bf(v.x), f2bf(v.y), f2bf(v.z), f2bf(v.w)};
            *(uint2*)&As[row * KP + c4] = *(uint2*)o;
        }
    } else {
        const unsigned short* A = (const unsigned short*)Ap0;   // zero-padded to Mpad
        int cpr = K >> 3;                        // 8-elem chunks per row
#pragma unroll 4
        for (int i = 0; i < 4; i++) {            // 64*K/8 = 1024 chunks (K=128)
            int idx = i * 256 + tid;
            int row = idx / cpr;
            int c8 = (idx - row * cpr) * 8;
            uint4 v = *(const uint4*)&A[(size_t)(row0 + row) * K + c8];
            *(uint4*)&As[row * KP + c8] = v;
        }
    }

    // ---- stage B for (head 0, k-step 0) into buf 0 ----
#define STAGE_B(hh, kk, buf)                                                      \
    {                                                                             \
        int k0s = (kk) << 5;                                                      \
        _Pragma("unroll") for (int i = 0; i < 2; i++) {                           \
            int c = (i * 4 + w) * 64 + lane;                                      \
            gload_lds16(BT + (size_t)((hh) * 128 + (c >> 2)) * K + k0s + (c & 3) * 8, \
                        (char*)Bs[buf] + (i * 4 + w) * 1024);                     \
        }                                                                         \
    }

    STAGE_B(0, 0, 0)

    f32x4 acc[2][4] = {};
    int cur = 0;
    int h = 0, ks = 0;
    int total = 3 * KS;
    for (int it = 0; it < total; ++it) {
        asm volatile("s_waitcnt vmcnt(0)" ::: "memory");
        __syncthreads();

        // stage-ahead next (h,ks) into the other buffer
        int nh = h, nks = ks + 1;
        if (nks == KS) { nh = h + 1; nks = 0; }
        if (nh < 3) STAGE_B(nh, nks, cur ^ 1)

        int k0 = ks << 5;
        bf16x8 af[2], bfr[4];
#pragma unroll
        for (int m = 0; m < 2; m++)
            af[m] = *(const bf16x8*)&As[(wr * 32 + m * 16 + frow) * KP + k0 + fk];
#pragma unroll
        for (int n = 0; n < 4; n++)
            bfr[n] = *(const bf16x8*)&Bs[cur][(wc * 64 + n * 16 + frow) * 32 + fk];
#pragma unroll
        for (int m = 0; m < 2; m++)
#pragma unroll
            for (int n = 0; n < 4; n++)
                acc[m][n] = __builtin_amdgcn_mfma_f32_16x16x32_bf16(af[m], bfr[n], acc[m][n], 0, 0, 0);

        if (ks == KS - 1) {
            // ---------------- epilogue for head h ----------------
            int ccol = lane & 15, crow = (lane >> 4) * 4;
            int col0 = h * 128;
#pragma unroll
            for (int m = 0; m < 2; m++)
#pragma unroll
                for (int n = 0; n < 4; n++)
#pragma unroll
                    for (int j = 0; j < 4; j++) {
                        int r = row0 + wr * 32 + m * 16 + crow + j;
                        int cc = col0 + wc * 64 + n * 16 + ccol;
                        C[(size_t)r * Ncols + cc] = f2bf(acc[m][n][j]);
                    }
            float as4[4], ad4[4];
#pragma unroll
            for (int n = 0; n < 4; n++) {
                int col_sub = wc * 64 + n * 16 + ccol;
                as4[n] = asrc[h * HID + col_sub];
                ad4[n] = adst[h * HID + col_sub];
            }
#pragma unroll
            for (int m = 0; m < 2; m++)
#pragma unroll
                for (int j = 0; j < 4; j++) {
                    float ps = 0.f, pd = 0.f;
#pragma unroll
                    for (int n = 0; n < 4; n++) {
                        float v = acc[m][n][j];
                        ps = fmaf(v, as4[n], ps);
                        pd = fmaf(v, ad4[n], pd);
                    }
#pragma unroll
                    for (int off = 1; off < 16; off <<= 1) {
                        ps += __shfl_xor(ps, off);
                        pd += __shfl_xor(pd, off);
                    }
                    if (ccol == 0) {
                        int row_sub = wr * 32 + m * 16 + crow + j;
                        esP[row_sub][wc] = ps;
                        edP[row_sub][wc] = pd;
                    }
                }
            __syncthreads();
            if (tid < 64) {
                int r = row0 + tid;
                if (r < Nnodes) {
                    es[(size_t)r * 4 + h] = esP[tid][0] + esP[tid][1];
                    ed[(size_t)r * 4 + h] = edP[tid][0] + edP[tid][1];
                }
            }
            // reset accumulator for next head
#pragma unroll
            for (int m = 0; m < 2; m++)
#pragma unroll
                for (int n = 0; n < 4; n++)
                    acc[m][n] = f32x4{0.f, 0.f, 0.f, 0.f};
            h++;
            ks = 0;
        } else {
            ks++;
        }
        cur ^= 1;
    }
#undef STAGE_B
}

// ---------------- per-edge weights (streamed w4, float4 logit gathers) ----------------

__global__ void k_edge_w(const int* __restrict__ ssrc, const int* __restrict__ sdst,
                         const float* __restrict__ es, const float* __restrict__ ed,
                         float4* __restrict__ w4, int E) {
    for (int j = blockIdx.x * blockDim.x + threadIdx.x; j < E; j += gridDim.x * blockDim.x) {
        int s = ssrc[j], d = sdst[j];
        float4 a = *(const float4*)&es[(size_t)s * 4];
        float4 b = *(const float4*)&ed[(size_t)d * 4];
        float w0 = __expf(lrelu(a.x + b.x));
        float w1 = __expf(lrelu(a.y + b.y));
        float w2 = __expf(lrelu(a.z + b.z));
        w4[j] = make_float4(w0, w1, w2, 0.f);
    }
}

// ---------------- wave-per-node aggregation (w4 streamed, den inline) ----------------
// Lane L holds uints {L, L+64, L+128} of the 192-uint H row = channels
// {2L,2L+1} of heads 0,1,2. No LDS, no barriers.

#define EDGE_UNROLL4(body)                                                       \
    int j = j0;                                                                  \
    for (; j + 4 <= j1; j += 4) {                                                \
        int si[4]; float4 wv[4]; unsigned uu[4][3];                              \
        _Pragma("unroll") for (int e = 0; e < 4; e++) si[e] = ssrc[j + e];       \
        _Pragma("unroll") for (int e = 0; e < 4; e++) wv[e] = w4[j + e];         \
        _Pragma("unroll") for (int e = 0; e < 4; e++) {                          \
            const unsigned* rp = Hu + (size_t)si[e] * 192 + L;                   \
            uu[e][0] = rp[0]; uu[e][1] = rp[64]; uu[e][2] = rp[128];             \
        }                                                                        \
        _Pragma("unroll") for (int e = 0; e < 4; e++) { body(wv[e], uu[e]) }     \
    }                                                                            \
    for (; j < j1; j++) {                                                        \
        int s1_ = ssrc[j]; float4 w_ = w4[j];                                    \
        const unsigned* rp = Hu + (size_t)s1_ * 192 + L;                         \
        unsigned u_[3] = {rp[0], rp[64], rp[128]};                               \
        { body(w_, u_) }                                                         \
    }

#define ACC3(wv, uv)                                                             \
    a0[0] = fmaf(wv.x, bflo(uv[0]), a0[0]); a1[0] = fmaf(wv.x, bfhi(uv[0]), a1[0]); \
    a0[1] = fmaf(wv.y, bflo(uv[1]), a0[1]); a1[1] = fmaf(wv.y, bfhi(uv[1]), a1[1]); \
    a0[2] = fmaf(wv.z, bflo(uv[2]), a0[2]); a1[2] = fmaf(wv.z, bfhi(uv[2]), a1[2]); \
    den0 += wv.x; den1 += wv.y; den2 += wv.z;

__global__ __launch_bounds__(256) void k_agg_mean(const unsigned* __restrict__ Hu,
                                                  const float4* __restrict__ w4,
                                                  const float* __restrict__ es,
                                                  const float* __restrict__ ed,
                                                  const int* __restrict__ offs,
                                                  const int* __restrict__ ssrc,
                                                  const float* __restrict__ b,
                                                  unsigned* __restrict__ out, int Nn) {
    int L = threadIdx.x & 63;
    int wstep = gridDim.x * 4;
    for (int n = blockIdx.x * 4 + (threadIdx.x >> 6); n < Nn; n += wstep) {
        float4 esn = *(const float4*)&es[(size_t)n * 4];
        float4 edn = *(const float4*)&ed[(size_t)n * 4];
        float s0 = __expf(lrelu(esn.x + edn.x));
        float s1 = __expf(lrelu(esn.y + edn.y));
        float s2 = __expf(lrelu(esn.z + edn.z));
        float den0 = s0, den1 = s1, den2 = s2;
        const unsigned* rp = Hu + (size_t)n * 192 + L;
        unsigned u0 = rp[0], u1 = rp[64], u2 = rp[128];
        float a0[3] = {s0 * bflo(u0), s1 * bflo(u1), s2 * bflo(u2)};
        float a1[3] = {s0 * bfhi(u0), s1 * bfhi(u1), s2 * bfhi(u2)};
        int j0 = offs[n], j1 = offs[n + 1];
        EDGE_UNROLL4(ACC3)
        float iv0 = 1.f / den0, iv1 = 1.f / den1, iv2 = 1.f / den2;
        int c0 = 2 * L;
        float2 bb = *(const float2*)&b[c0];
        float m0 = (a0[0] * iv0 + a0[1] * iv1 + a0[2] * iv2) * (1.f / 3.f) + bb.x;
        float m1 = (a1[0] * iv0 + a1[1] * iv1 + a1[2] * iv2) * (1.f / 3.f) + bb.y;
        unsigned short o[2] = {f2bf(rrelu(m0)), f2bf(rrelu(m1))};
        out[(size_t)n * 64 + L] = *(unsigned*)o;
    }
}

__global__ __launch_bounds__(256) void k_agg_cat_final(const unsigned* __restrict__ Hu,
                                                       const float4* __restrict__ w4,
                                                       const float* __restrict__ es,
                                                       const float* __restrict__ ed,
                                                       const int* __restrict__ offs,
                                                       const int* __restrict__ ssrc,
                                                       const float* __restrict__ b,
                                                       const float* __restrict__ Wl,
                                                       const float* __restrict__ bl,
                                                       float* __restrict__ out, int Nn) {
    int L = threadIdx.x & 63;
    int wstep = gridDim.x * 4;
    for (int n = blockIdx.x * 4 + (threadIdx.x >> 6); n < Nn; n += wstep) {
        float4 esn = *(const float4*)&es[(size_t)n * 4];
        float4 edn = *(const float4*)&ed[(size_t)n * 4];
        float s0 = __expf(lrelu(esn.x + edn.x));
        float s1 = __expf(lrelu(esn.y + edn.y));
        float s2 = __expf(lrelu(esn.z + edn.z));
        float den0 = s0, den1 = s1, den2 = s2;
        const unsigned* rp = Hu + (size_t)n * 192 + L;
        unsigned u0 = rp[0], u1 = rp[64], u2 = rp[128];
        float a0[3] = {s0 * bflo(u0), s1 * bflo(u1), s2 * bflo(u2)};
        float a1[3] = {s0 * bfhi(u0), s1 * bfhi(u1), s2 * bfhi(u2)};
        int j0 = offs[n], j1 = offs[n + 1];
        EDGE_UNROLL4(ACC3)
        float ivv[3] = {1.f / den0, 1.f / den1, 1.f / den2};
        float p = 0.f;
#pragma unroll
        for (int k = 0; k < 3; k++) {
            int col = k * HID + 2 * L;
            float2 bb = *(const float2*)&b[col];
            float2 wl = *(const float2*)&Wl[col];
            float r0 = rrelu(a0[k] * ivv[k] + bb.x);
            float r1 = rrelu(a1[k] * ivv[k] + bb.y);
            p = fmaf(r0, wl.x, p);
            p = fmaf(r1, wl.y, p);
        }
#pragma unroll
        for (int off = 32; off > 0; off >>= 1) p += __shfl_down(p, off);
        if (L == 0) out[n] = 1.f / (1.f + __expf(-(p + bl[0])));
    }
}

// ---------------- launch ----------------

extern "C" void kernel_launch(void* const* d_in, const int* in_sizes, int n_in,
                              void* d_out, int out_size, void* d_ws, size_t ws_size,
                              hipStream_t stream) {
    const float* z   = (const float*)d_in[0];
    const float* x   = (const float*)d_in[1];
    const int*   ei  = (const int*)d_in[2];
    const float* W1  = (const float*)d_in[3];
    const float* a1s = (const float*)d_in[4];
    const float* a1d = (const float*)d_in[5];
    const float* b1  = (const float*)d_in[6];
    const float* W2  = (const float*)d_in[7];
    const float* a2s = (const float*)d_in[8];
    const float* a2d = (const float*)d_in[9];
    const float* b2  = (const float*)d_in[10];
    const float* Wl  = (const float*)d_in[11];
    const float* bl  = (const float*)d_in[12];
    float* outp = (float*)d_out;

    int Nn = in_sizes[0] / 128;
    int E  = in_sizes[2] / 2;
    int Mpad = (Nn + 127) & ~127;
    int nb = (Nn + SC_CHUNK - 1) / SC_CHUNK;

    char* p = (char*)d_ws;
    auto carve = [&](size_t bytes) -> char* {
        char* r = p;
        p += (bytes + 255) & ~(size_t)255;
        return r;
    };
    int*            offs   = (int*)carve((size_t)(Nn + 1) * 4);
    int*            cursor = (int*)carve((size_t)Nn * 4);
    int*            ssrc   = (int*)carve((size_t)E * 4);
    int*            sdst   = (int*)carve((size_t)E * 4);
    int*            bsum   = (int*)carve((size_t)(nb + 1) * 4);
    int*            bpre   = (int*)carve((size_t)(nb + 1) * 4);
    float*          e1s    = (float*)carve((size_t)Mpad * 16);
    float*          e1d    = (float*)carve((size_t)Mpad * 16);
    float4*         w4     = (float4*)carve((size_t)E * 16);
    unsigned short* W1T    = (unsigned short*)carve((size_t)FDIM * 256 * 2);
    unsigned short* W2T    = (unsigned short*)carve((size_t)FDIM * 128 * 2);
    unsigned short* Hbf    = (unsigned short*)carve((size_t)Mpad * FDIM * 2);
    unsigned short* H2in   = (unsigned short*)carve((size_t)Mpad * 128 * 2);

    const int* srcI = ei;
    const int* dstI = ei + E;

    // CSR build
    hipMemsetAsync(cursor, 0, (size_t)Nn * 4, stream);
    k_hist<<<1024, 256, 0, stream>>>(dstI, E, cursor);
    k_scan1<<<nb, SC_T, 0, stream>>>(cursor, offs, bsum, Nn);
    k_scan2<<<1, 256, 0, stream>>>(bsum, bpre, nb);
    k_scan3<<<(Nn + 255) / 256, 256, 0, stream>>>(offs, bpre, cursor, Nn, nb);
    k_scatter<<<1024, 256, 0, stream>>>(srcI, dstI, E, cursor, ssrc, sdst);

    // weight converts (single dispatch)
    k_cvt_wt2<<<2 * FDIM, 256, 0, stream>>>(W1, W1T, W2, W2T);
    hipMemsetAsync(H2in + (size_t)Nn * 128, 0, (size_t)(Mpad - Nn) * 128 * 2, stream);

    int gg = Mpad / 64;

    // Layer 1 (fp32-A GEMM + fused logits)
    k_gemm<true><<<gg, 256, 0, stream>>>(z, x, Nn, W1T, Hbf, 256, FDIM,
                                         a1s, a1d, e1s, e1d, Nn);
    k_edge_w<<<1024, 256, 0, stream>>>(ssrc, sdst, e1s, e1d, w4, E);
    k_agg_mean<<<2048, 256, 0, stream>>>((const unsigned*)Hbf, w4, e1s, e1d, offs,
                                         ssrc, b1, (unsigned*)H2in, Nn);

    // Layer 2 (bf16 GEMM + fused logits, aggregate + linear + sigmoid)
    k_gemm<false><<<gg, 256, 0, stream>>>(H2in, nullptr, Mpad, W2T, Hbf, 128, FDIM,
                                          a2s, a2d, e1s, e1d, Nn);
    k_edge_w<<<1024, 256, 0, stream>>>(ssrc, sdst, e1s, e1d, w4, E);
    k_agg_cat_final<<<2048, 256, 0, stream>>>((const unsigned*)Hbf, w4, e1s, e1d, offs,
                                              ssrc, b2, Wl, bl, outp, Nn);
}

// Round 13
// 249.122 us; speedup vs baseline: 1.1108x; 1.1108x over previous
//
#include <hip/hip_runtime.h>
#include <stdint.h>

#define HEADS 3
#define HID 128
#define FDIM (HEADS * HID)   // 384

typedef __attribute__((ext_vector_type(8))) short bf16x8;
typedef __attribute__((ext_vector_type(4))) float f32x4;

__device__ __forceinline__ float lrelu(float x) { return x >= 0.f ? x : 0.2f * x; }
__device__ __forceinline__ float rrelu(float x) {
    const float SLOPE = (1.0f / 8.0f + 1.0f / 3.0f) * 0.5f;
    return x >= 0.f ? x : SLOPE * x;
}
__device__ __forceinline__ unsigned short f2bf(float f) {
    union { float f; unsigned u; } c; c.f = f;
    unsigned r = c.u + 0x7FFF + ((c.u >> 16) & 1);   // RNE
    return (unsigned short)(r >> 16);
}
__device__ __forceinline__ float bflo(unsigned u) {
    union { unsigned u; float f; } c; c.u = u << 16; return c.f;
}
__device__ __forceinline__ float bfhi(unsigned u) {
    union { unsigned u; float f; } c; c.u = u & 0xffff0000u; return c.f;
}

__device__ __forceinline__ void gload_lds16(const void* g, void* l) {
    __builtin_amdgcn_global_load_lds(
        (const __attribute__((address_space(1))) void*)g,
        (__attribute__((address_space(3))) void*)l, 16, 0, 0);
}

// ---------------- CSR build (counting sort by dst) ----------------

__global__ void k_hist(const int* __restrict__ dst, int E, int* __restrict__ cnt) {
    for (int i = blockIdx.x * blockDim.x + threadIdx.x; i < E; i += gridDim.x * blockDim.x)
        atomicAdd(&cnt[dst[i]], 1);
}

#define SC_T 256
#define SC_E 8
#define SC_CHUNK (SC_T * SC_E)   // 2048

__global__ __launch_bounds__(SC_T) void k_scan1(const int* __restrict__ cnt,
                                                int* __restrict__ exc,
                                                int* __restrict__ bsum, int n) {
    __shared__ int sm[SC_T];
    int b = blockIdx.x, t = threadIdx.x;
    int base = b * SC_CHUNK + t * SC_E;
    int v[SC_E];
    int s = 0;
#pragma unroll
    for (int i = 0; i < SC_E; i++) {
        int idx = base + i;
        v[i] = (idx < n) ? cnt[idx] : 0;
        s += v[i];
    }
    sm[t] = s;
    __syncthreads();
    for (int off = 1; off < SC_T; off <<= 1) {
        int x = (t >= off) ? sm[t - off] : 0;
        __syncthreads();
        sm[t] += x;
        __syncthreads();
    }
    int run = sm[t] - s;
    if (t == SC_T - 1) bsum[b] = sm[t];
#pragma unroll
    for (int i = 0; i < SC_E; i++) {
        int idx = base + i;
        if (idx < n) exc[idx] = run;
        run += v[i];
    }
}

__global__ __launch_bounds__(256) void k_scan2(const int* __restrict__ bsum,
                                               int* __restrict__ bpre, int nb) {
    __shared__ int sm[256];
    int t = threadIdx.x;
    int v = (t < nb) ? bsum[t] : 0;
    sm[t] = v;
    __syncthreads();
    for (int off = 1; off < 256; off <<= 1) {
        int x = (t >= off) ? sm[t - off] : 0;
        __syncthreads();
        sm[t] += x;
        __syncthreads();
    }
    if (t < nb) bpre[t + 1] = sm[t];
    if (t == 0) bpre[0] = 0;
}

__global__ void k_scan3(int* __restrict__ offs, const int* __restrict__ bpre,
                        int* __restrict__ cursor, int n, int nb) {
    int i = blockIdx.x * blockDim.x + threadIdx.x;
    if (i < n) {
        int o = offs[i] + bpre[i / SC_CHUNK];
        offs[i] = o;
        cursor[i] = o;
    }
    if (i == 0) offs[n] = bpre[nb];
}

__global__ void k_scatter(const int* __restrict__ src, const int* __restrict__ dst, int E,
                          int* __restrict__ cursor, int* __restrict__ ssrc,
                          int* __restrict__ sdst) {
    for (int i = blockIdx.x * blockDim.x + threadIdx.x; i < E; i += gridDim.x * blockDim.x) {
        int d = dst[i];
        int p = atomicAdd(&cursor[d], 1);
        ssrc[p] = src[i];
        sdst[p] = d;
    }
}

// ---------------- bf16 convert: W1^T and W2^T in one dispatch ----------------

__global__ void k_cvt_wt2(const float* __restrict__ W1, unsigned short* __restrict__ W1T,
                          const float* __restrict__ W2, unsigned short* __restrict__ W2T) {
    int b = blockIdx.x;
    if (b < FDIM) {
        for (int k = threadIdx.x; k < 256; k += blockDim.x)
            W1T[(size_t)b * 256 + k] = f2bf(W1[(size_t)k * FDIM + b]);
    } else {
        int n = b - FDIM;
        for (int k = threadIdx.x; k < 128; k += blockDim.x)
            W2T[(size_t)n * 128 + k] = f2bf(W2[(size_t)k * FDIM + n]);
    }
}

// ---------------- bf16 MFMA GEMM (64x128 tile) + fused logits epilogue ----------------
// es/ed are [N,4] stride-4 for float4 reads in k_edge_w / agg kernels.

template <bool F32A>
__global__ __launch_bounds__(256) void k_gemm(
    const void* __restrict__ Ap0, const void* __restrict__ Ap1, int Nn,
    const unsigned short* __restrict__ BT,
    unsigned short* __restrict__ C,
    int K, int Ncols,
    const float* __restrict__ asrc, const float* __restrict__ adst,
    float* __restrict__ es, float* __restrict__ ed, int Nnodes) {
    __shared__ __align__(16) unsigned short As[64 * 32];
    __shared__ __align__(16) unsigned short Bs[128 * 32];
    __shared__ float esP[64][2], edP[64][2];
    int tid = threadIdx.x;
    int w = tid >> 6, lane = tid & 63;
    int row0 = blockIdx.x * 64;
    int head = blockIdx.y;
    int col0 = head * 128;
    int wr = w >> 1, wc = w & 1;     // wave: rows wr*32..+32, cols wc*64..+64

    f32x4 acc[2][4] = {};
    int frow = lane & 15;
    int fk = (lane >> 4) * 8;

    const float* zf = (const float*)Ap0;
    const float* xf = (const float*)Ap1;
    float4 va[2];
    if (F32A) {
#pragma unroll
        for (int i = 0; i < 2; i++) {
            int idx = i * 256 + tid;
            int row = idx >> 3, c4 = (idx & 7) * 4;
            int gr = row0 + row;
            const float* sp = zf + (size_t)gr * 128 + c4;      // k0 = 0
            va[i] = (gr < Nn) ? *(const float4*)sp : make_float4(0.f, 0.f, 0.f, 0.f);
        }
    }

    for (int k0 = 0; k0 < K; k0 += 32) {
        // stage B (async)
#pragma unroll
        for (int i = 0; i < 2; i++) {
            int c = (i * 4 + w) * 64 + lane;
            gload_lds16(BT + (size_t)(col0 + (c >> 2)) * K + k0 + (c & 3) * 8,
                        (char*)Bs + (i * 4 + w) * 1024);
        }
        if (F32A) {
#pragma unroll
            for (int i = 0; i < 2; i++) {
                int idx = i * 256 + tid;
                unsigned short o[4] = {f2bf(va[i].x), f2bf(va[i].y),
                                       f2bf(va[i].z), f2bf(va[i].w)};
                *(uint2*)((char*)As + (size_t)idx * 8) = *(uint2*)o;
            }
        } else {
            const unsigned short* A = (const unsigned short*)Ap0;
            int c = tid;
            gload_lds16(A + (size_t)(row0 + (c >> 2)) * K + k0 + (c & 3) * 8,
                        (char*)As + w * 1024);
        }
        asm volatile("s_waitcnt vmcnt(0)" ::: "memory");
        __syncthreads();

        // prefetch next A tile (in flight through MFMA)
        if (F32A && (k0 + 32 < K)) {
            int kn = k0 + 32;
#pragma unroll
            for (int i = 0; i < 2; i++) {
                int idx = i * 256 + tid;
                int row = idx >> 3, c4 = (idx & 7) * 4;
                int gr = row0 + row;
                const float* sp = (kn < 128)
                                      ? (zf + (size_t)gr * 128 + kn + c4)
                                      : (xf + (size_t)gr * 128 + (kn - 128) + c4);
                va[i] = (gr < Nn) ? *(const float4*)sp : make_float4(0.f, 0.f, 0.f, 0.f);
            }
        }

        bf16x8 af[2], bfr[4];
#pragma unroll
        for (int m = 0; m < 2; m++)
            af[m] = *(const bf16x8*)&As[(wr * 32 + m * 16 + frow) * 32 + fk];
#pragma unroll
        for (int n = 0; n < 4; n++)
            bfr[n] = *(const bf16x8*)&Bs[(wc * 64 + n * 16 + frow) * 32 + fk];
#pragma unroll
        for (int m = 0; m < 2; m++)
#pragma unroll
            for (int n = 0; n < 4; n++)
                acc[m][n] = __builtin_amdgcn_mfma_f32_16x16x32_bf16(af[m], bfr[n], acc[m][n], 0, 0, 0);
        __syncthreads();
    }

    int ccol = lane & 15, crow = (lane >> 4) * 4;

    // C write
#pragma unroll
    for (int m = 0; m < 2; m++)
#pragma unroll
        for (int n = 0; n < 4; n++)
#pragma unroll
            for (int j = 0; j < 4; j++) {
                int r = row0 + wr * 32 + m * 16 + crow + j;
                int cc = col0 + wc * 64 + n * 16 + ccol;
                C[(size_t)r * Ncols + cc] = f2bf(acc[m][n][j]);
            }

    // fused logits
    float as4[4], ad4[4];
#pragma unroll
    for (int n = 0; n < 4; n++) {
        int col_sub = wc * 64 + n * 16 + ccol;
        as4[n] = asrc[head * HID + col_sub];
        ad4[n] = adst[head * HID + col_sub];
    }
#pragma unroll
    for (int m = 0; m < 2; m++)
#pragma unroll
        for (int j = 0; j < 4; j++) {
            float ps = 0.f, pd = 0.f;
#pragma unroll
            for (int n = 0; n < 4; n++) {
                float v = acc[m][n][j];
                ps = fmaf(v, as4[n], ps);
                pd = fmaf(v, ad4[n], pd);
            }
#pragma unroll
            for (int off = 1; off < 16; off <<= 1) {
                ps += __shfl_xor(ps, off);
                pd += __shfl_xor(pd, off);
            }
            if (ccol == 0) {
                int row_sub = wr * 32 + m * 16 + crow + j;
                esP[row_sub][wc] = ps;
                edP[row_sub][wc] = pd;
            }
        }
    __syncthreads();
    if (tid < 64) {
        int r = row0 + tid;
        if (r < Nnodes) {
            es[(size_t)r * 4 + head] = esP[tid][0] + esP[tid][1];
            ed[(size_t)r * 4 + head] = edP[tid][0] + edP[tid][1];
        }
    }
}

// ---------------- per-edge weights (streamed w4, float4 logit gathers) ----------------

__global__ void k_edge_w(const int* __restrict__ ssrc, const int* __restrict__ sdst,
                         const float* __restrict__ es, const float* __restrict__ ed,
                         float4* __restrict__ w4, int E) {
    for (int j = blockIdx.x * blockDim.x + threadIdx.x; j < E; j += gridDim.x * blockDim.x) {
        int s = ssrc[j], d = sdst[j];
        float4 a = *(const float4*)&es[(size_t)s * 4];
        float4 b = *(const float4*)&ed[(size_t)d * 4];
        float w0 = __expf(lrelu(a.x + b.x));
        float w1 = __expf(lrelu(a.y + b.y));
        float w2 = __expf(lrelu(a.z + b.z));
        w4[j] = make_float4(w0, w1, w2, 0.f);
    }
}

// ---------------- wave-per-node aggregation (w4 streamed, den inline) ----------------
// Lane L holds uints {L, L+64, L+128} of the 192-uint H row = channels
// {2L,2L+1} of heads 0,1,2. No LDS, no barriers.

#define EDGE_UNROLL4(body)                                                       \
    int j = j0;                                                                  \
    for (; j + 4 <= j1; j += 4) {                                                \
        int si[4]; float4 wv[4]; unsigned uu[4][3];                              \
        _Pragma("unroll") for (int e = 0; e < 4; e++) si[e] = ssrc[j + e];       \
        _Pragma("unroll") for (int e = 0; e < 4; e++) wv[e] = w4[j + e];         \
        _Pragma("unroll") for (int e = 0; e < 4; e++) {                          \
            const unsigned* rp = Hu + (size_t)si[e] * 192 + L;                   \
            uu[e][0] = rp[0]; uu[e][1] = rp[64]; uu[e][2] = rp[128];             \
        }                                                                        \
        _Pragma("unroll") for (int e = 0; e < 4; e++) { body(wv[e], uu[e]) }     \
    }                                                                            \
    for (; j < j1; j++) {                                                        \
        int s1_ = ssrc[j]; float4 w_ = w4[j];                                    \
        const unsigned* rp = Hu + (size_t)s1_ * 192 + L;                         \
        unsigned u_[3] = {rp[0], rp[64], rp[128]};                               \
        { body(w_, u_) }                                                         \
    }

#define ACC3(wv, uv)                                                             \
    a0[0] = fmaf(wv.x, bflo(uv[0]), a0[0]); a1[0] = fmaf(wv.x, bfhi(uv[0]), a1[0]); \
    a0[1] = fmaf(wv.y, bflo(uv[1]), a0[1]); a1[1] = fmaf(wv.y, bfhi(uv[1]), a1[1]); \
    a0[2] = fmaf(wv.z, bflo(uv[2]), a0[2]); a1[2] = fmaf(wv.z, bfhi(uv[2]), a1[2]); \
    den0 += wv.x; den1 += wv.y; den2 += wv.z;

__global__ __launch_bounds__(256) void k_agg_mean(const unsigned* __restrict__ Hu,
                                                  const float4* __restrict__ w4,
                                                  const float* __restrict__ es,
                                                  const float* __restrict__ ed,
                                                  const int* __restrict__ offs,
                                                  const int* __restrict__ ssrc,
                                                  const float* __restrict__ b,
                                                  unsigned* __restrict__ out, int Nn) {
    int L = threadIdx.x & 63;
    int wstep = gridDim.x * 4;
    for (int n = blockIdx.x * 4 + (threadIdx.x >> 6); n < Nn; n += wstep) {
        float4 esn = *(const float4*)&es[(size_t)n * 4];
        float4 edn = *(const float4*)&ed[(size_t)n * 4];
        float s0 = __expf(lrelu(esn.x + edn.x));
        float s1 = __expf(lrelu(esn.y + edn.y));
        float s2 = __expf(lrelu(esn.z + edn.z));
        float den0 = s0, den1 = s1, den2 = s2;
        const unsigned* rp = Hu + (size_t)n * 192 + L;
        unsigned u0 = rp[0], u1 = rp[64], u2 = rp[128];
        float a0[3] = {s0 * bflo(u0), s1 * bflo(u1), s2 * bflo(u2)};
        float a1[3] = {s0 * bfhi(u0), s1 * bfhi(u1), s2 * bfhi(u2)};
        int j0 = offs[n], j1 = offs[n + 1];
        EDGE_UNROLL4(ACC3)
        float iv0 = 1.f / den0, iv1 = 1.f / den1, iv2 = 1.f / den2;
        int c0 = 2 * L;
        float2 bb = *(const float2*)&b[c0];
        float m0 = (a0[0] * iv0 + a0[1] * iv1 + a0[2] * iv2) * (1.f / 3.f) + bb.x;
        float m1 = (a1[0] * iv0 + a1[1] * iv1 + a1[2] * iv2) * (1.f / 3.f) + bb.y;
        unsigned short o[2] = {f2bf(rrelu(m0)), f2bf(rrelu(m1))};
        out[(size_t)n * 64 + L] = *(unsigned*)o;
    }
}

__global__ __launch_bounds__(256) void k_agg_cat_final(const unsigned* __restrict__ Hu,
                                                       const float4* __restrict__ w4,
                                                       const float* __restrict__ es,
                                                       const float* __restrict__ ed,
                                                       const int* __restrict__ offs,
                                                       const int* __restrict__ ssrc,
                                                       const float* __restrict__ b,
                                                       const float* __restrict__ Wl,
                                                       const float* __restrict__ bl,
                                                       float* __restrict__ out, int Nn) {
    int L = threadIdx.x & 63;
    int wstep = gridDim.x * 4;
    for (int n = blockIdx.x * 4 + (threadIdx.x >> 6); n < Nn; n += wstep) {
        float4 esn = *(const float4*)&es[(size_t)n * 4];
        float4 edn = *(const float4*)&ed[(size_t)n * 4];
        float s0 = __expf(lrelu(esn.x + edn.x));
        float s1 = __expf(lrelu(esn.y + edn.y));
        float s2 = __expf(lrelu(esn.z + edn.z));
        float den0 = s0, den1 = s1, den2 = s2;
        const unsigned* rp = Hu + (size_t)n * 192 + L;
        unsigned u0 = rp[0], u1 = rp[64], u2 = rp[128];
        float a0[3] = {s0 * bflo(u0), s1 * bflo(u1), s2 * bflo(u2)};
        float a1[3] = {s0 * bfhi(u0), s1 * bfhi(u1), s2 * bfhi(u2)};
        int j0 = offs[n], j1 = offs[n + 1];
        EDGE_UNROLL4(ACC3)
        float ivv[3] = {1.f / den0, 1.f / den1, 1.f / den2};
        float p = 0.f;
#pragma unroll
        for (int k = 0; k < 3; k++) {
            int col = k * HID + 2 * L;
            float2 bb = *(const float2*)&b[col];
            float2 wl = *(const float2*)&Wl[col];
            float r0 = rrelu(a0[k] * ivv[k] + bb.x);
            float r1 = rrelu(a1[k] * ivv[k] + bb.y);
            p = fmaf(r0, wl.x, p);
            p = fmaf(r1, wl.y, p);
        }
#pragma unroll
        for (int off = 32; off > 0; off >>= 1) p += __shfl_down(p, off);
        if (L == 0) out[n] = 1.f / (1.f + __expf(-(p + bl[0])));
    }
}

// ---------------- launch ----------------

extern "C" void kernel_launch(void* const* d_in, const int* in_sizes, int n_in,
                              void* d_out, int out_size, void* d_ws, size_t ws_size,
                              hipStream_t stream) {
    const float* z   = (const float*)d_in[0];
    const float* x   = (const float*)d_in[1];
    const int*   ei  = (const int*)d_in[2];
    const float* W1  = (const float*)d_in[3];
    const float* a1s = (const float*)d_in[4];
    const float* a1d = (const float*)d_in[5];
    const float* b1  = (const float*)d_in[6];
    const float* W2  = (const float*)d_in[7];
    const float* a2s = (const float*)d_in[8];
    const float* a2d = (const float*)d_in[9];
    const float* b2  = (const float*)d_in[10];
    const float* Wl  = (const float*)d_in[11];
    const float* bl  = (const float*)d_in[12];
    float* outp = (float*)d_out;

    int Nn = in_sizes[0] / 128;
    int E  = in_sizes[2] / 2;
    int Mpad = (Nn + 127) & ~127;
    int nb = (Nn + SC_CHUNK - 1) / SC_CHUNK;

    char* p = (char*)d_ws;
    auto carve = [&](size_t bytes) -> char* {
        char* r = p;
        p += (bytes + 255) & ~(size_t)255;
        return r;
    };
    int*            offs   = (int*)carve((size_t)(Nn + 1) * 4);
    int*            cursor = (int*)carve((size_t)Nn * 4);
    int*            ssrc   = (int*)carve((size_t)E * 4);
    int*            sdst   = (int*)carve((size_t)E * 4);
    int*            bsum   = (int*)carve((size_t)(nb + 1) * 4);
    int*            bpre   = (int*)carve((size_t)(nb + 1) * 4);
    float*          e1s    = (float*)carve((size_t)Mpad * 16);
    float*          e1d    = (float*)carve((size_t)Mpad * 16);
    float4*         w4     = (float4*)carve((size_t)E * 16);
    unsigned short* W1T    = (unsigned short*)carve((size_t)FDIM * 256 * 2);
    unsigned short* W2T    = (unsigned short*)carve((size_t)FDIM * 128 * 2);
    unsigned short* Hbf    = (unsigned short*)carve((size_t)Mpad * FDIM * 2);
    unsigned short* H2in   = (unsigned short*)carve((size_t)Mpad * 128 * 2);

    const int* srcI = ei;
    const int* dstI = ei + E;

    // CSR build
    hipMemsetAsync(cursor, 0, (size_t)Nn * 4, stream);
    k_hist<<<1024, 256, 0, stream>>>(dstI, E, cursor);
    k_scan1<<<nb, SC_T, 0, stream>>>(cursor, offs, bsum, Nn);
    k_scan2<<<1, 256, 0, stream>>>(bsum, bpre, nb);
    k_scan3<<<(Nn + 255) / 256, 256, 0, stream>>>(offs, bpre, cursor, Nn, nb);
    k_scatter<<<1024, 256, 0, stream>>>(srcI, dstI, E, cursor, ssrc, sdst);

    // weight converts (single dispatch)
    k_cvt_wt2<<<2 * FDIM, 256, 0, stream>>>(W1, W1T, W2, W2T);
    hipMemsetAsync(H2in + (size_t)Nn * 128, 0, (size_t)(Mpad - Nn) * 128 * 2, stream);

    dim3 gg(Mpad / 64, FDIM / 128);

    // Layer 1 (fp32-A GEMM + fused logits)
    k_gemm<true><<<gg, 256, 0, stream>>>(z, x, Nn, W1T, Hbf, 256, FDIM,
                                         a1s, a1d, e1s, e1d, Nn);
    k_edge_w<<<1024, 256, 0, stream>>>(ssrc, sdst, e1s, e1d, w4, E);
    k_agg_mean<<<2048, 256, 0, stream>>>((const unsigned*)Hbf, w4, e1s, e1d, offs,
                                         ssrc, b1, (unsigned*)H2in, Nn);

    // Layer 2 (bf16 GEMM + fused logits, aggregate + linear + sigmoid)
    k_gemm<false><<<gg, 256, 0, stream>>>(H2in, nullptr, Mpad, W2T, Hbf, 128, FDIM,
                                          a2s, a2d, e1s, e1d, Nn);
    k_edge_w<<<1024, 256, 0, stream>>>(ssrc, sdst, e1s, e1d, w4, E);
    k_agg_cat_final<<<2048, 256, 0, stream>>>((const unsigned*)Hbf, w4, e1s, e1d, offs,
                                              ssrc, b2, Wl, bl, outp, Nn);
}